// Round 6
// baseline (619.346 us; speedup 1.0000x reference)
//
#include <hip/hip_runtime.h>
#include <hip/hip_bf16.h>

// VQ-VAE VectorQuantizer — round 6: fused 1-term fp16 screen + exact rescore.
//   S^T = (-2E)*X^T via 32x32x16 f16 MFMA, K = 256 (+norm-kb: hi/lo fp16 of
//   ||e||^2 against B=ones). Per-lane top-4 with the code index packed into
//   the score's low 10 mantissa bits (quantization ~0.06 << NN gaps ~18),
//   sorted via a min/max network (9 VALU/score). Exact fp32 rescore of the
//   4 candidates, z_q write and loss accumulation fused into the same kernel.
// Occupancy: grid 512 x 256 thr, 34 KB single-buffer LDS -> 4 blocks/CU,
//   16 waves/CU (4/SIMD); __launch_bounds__(256,4) caps VGPR at 128.

#define EMBED_DIM 256
#define N_EMBED   1024
#define HW        4096
#define NPIX      65536
#define BETA      0.25f

typedef _Float16 h8v __attribute__((ext_vector_type(8)));
typedef __attribute__((ext_vector_type(16))) float f32x16;

// ---------------- workspace layout (float offsets) ----------------
#define NW_LOSS   0       // [0] = loss accumulator
#define NW_NORMS  64      // 1024 floats
#define NW_ES2    1152    // 17*32*64 h8v = 278528 halves = 139264 floats
#define NW_END    140416
#define NEED_BYTES ((size_t)NW_END * 4)

// fallback (round-1) layout
#define WS_ET_OFF    64
#define WS_NORM_OFF  (64 + EMBED_DIM * N_EMBED)

#define CHUNK_BYTES (34 * 1024)   // 17 akb x 2 cb x 1 KB per chunk of 64 codes

__device__ inline void async16(const void* g, void* s) {
    __builtin_amdgcn_global_load_lds(
        (const __attribute__((address_space(1))) unsigned int*)g,
        (__attribute__((address_space(3))) unsigned int*)s, 16, 0, 0);
}

// pack code index into low 10 mantissa bits: one v_and_or_b32
__device__ inline float pack_si(float s, int j) {
    return __int_as_float((__float_as_int(s) & 0xFFFFFC00) | j);
}

// sorted-4 insert via min/max network (no branches, no index regs)
__device__ inline void ins4(float p, float v[4]) {
    float m0 = fmaxf(v[0], p);  v[0] = fminf(v[0], p);
    float m1 = fmaxf(v[1], m0); v[1] = fminf(v[1], m0);
    float m2 = fmaxf(v[2], m1); v[2] = fminf(v[2], m1);
    v[3] = fminf(v[3], m2);
}

// ======================= prep kernels =======================

__global__ void k_norms(const float* __restrict__ emb, float* __restrict__ norms,
                        float* __restrict__ loss_acc) {
    int j = blockIdx.x;
    int lane = threadIdx.x;
    const float* row = emb + j * EMBED_DIM;
    float s = 0.f;
    #pragma unroll
    for (int r = 0; r < 4; ++r) { float v = row[lane + r * 64]; s += v * v; }
    #pragma unroll
    for (int off = 32; off; off >>= 1) s += __shfl_down(s, off, 64);
    if (lane == 0) norms[j] = s;
    if (blockIdx.x == 0 && lane == 0) loss_acc[0] = 0.f;
}

// es2 frag t = (akb*32 + cb)*64 + lane ; akb 0-15 = fp16(-2e), 16 = norm kb.
// A layout: m = cb*32 + (lane&31), k = (lane>>5)*8 + j ; c = akb*16 + k.
__global__ void k_prep_e2(const float* __restrict__ emb, const float* __restrict__ norms,
                          _Float16* __restrict__ es2) {
    int t = blockIdx.x * 256 + threadIdx.x;       // 17*32*64 = 34816
    if (t >= 17 * 32 * 64) return;
    int lane = t & 63;
    int cb   = (t >> 6) & 31;
    int akb  = t >> 11;                           // 0..16
    int m = cb * 32 + (lane & 31);
    int h = lane >> 5;
    _Float16 o[8];
    if (akb < 16) {
        #pragma unroll
        for (int j = 0; j < 8; ++j) {
            int c = akb * 16 + h * 8 + j;
            o[j] = (_Float16)(-2.0f * emb[m * EMBED_DIM + c]);
        }
    } else {
        float nm = norms[m];
        _Float16 nh = (_Float16)nm;
        _Float16 nl = (_Float16)(nm - (float)nh);
        #pragma unroll
        for (int j = 0; j < 8; ++j) o[j] = (_Float16)0.f;
        if (h == 0) { o[0] = nh; o[1] = nl; }
    }
    *(h8v*)(es2 + (size_t)t * 8) = *(h8v*)o;
}

// ======================= fused screen + rescore =======================

__global__ __launch_bounds__(256, 4)
void k_screen5(const float* __restrict__ z, const _Float16* __restrict__ es2,
               const float* __restrict__ emb, float* __restrict__ out,
               float* __restrict__ loss_acc) {
    __shared__ __align__(16) char abuf[CHUNK_BYTES];   // 34 KB, single buffer

    const int tid  = threadIdx.x;
    const int lane = tid & 63;
    const int wv   = tid >> 6;                    // 0..3
    const int pxl  = lane & 31;
    const int h    = lane >> 5;
    const int h4   = h * 4;
    const int ln16 = lane * 16;

    // whole block lives in one batch image: 4096/128 = 32 blocks per image
    const int px = blockIdx.x * 128 + wv * 32 + pxl;
    const int b  = px >> 12, hw = px & 4095;
    const float* zb = z + (size_t)b * (EMBED_DIM * HW) + hw;

    // ---- B fragments: fp16(x), this wave's 32 pixels ----
    h8v bx[16];
    #pragma unroll
    for (int kh = 0; kh < 16; ++kh) {
        const int c0 = kh * 16 + h * 8;
        _Float16 o[8];
        #pragma unroll
        for (int j = 0; j < 8; ++j)
            o[j] = (_Float16)zb[(size_t)(c0 + j) * HW];
        bx[kh] = *(h8v*)o;
    }

    h8v bn;                                       // norm-kb B: B[0..1][n] = 1
    #pragma unroll
    for (int j = 0; j < 8; ++j) bn[j] = (_Float16)0.f;
    if (lane < 32) { bn[0] = (_Float16)1.f; bn[1] = (_Float16)1.f; }

    float v[4] = {3.3e38f, 3.3e38f, 3.3e38f, 3.3e38f};

    for (int c = 0; c < 16; ++c) {
        __syncthreads();                          // prev chunk's LDS reads done
        for (int f = wv; f < 34; f += 4) {
            const _Float16* src = es2 +
                ((size_t)((f >> 1) * 32 + c * 2 + (f & 1)) * 64 + lane) * 8;
            async16(src, abuf + f * 1024 + ln16);
        }
        __syncthreads();                          // staging visible (vmcnt drained)

        f32x16 acc0, acc1;
        #pragma unroll
        for (int r = 0; r < 16; ++r) { acc0[r] = 0.f; acc1[r] = 0.f; }

        h8v a0 = *(const h8v*)(abuf + 0 * 1024 + ln16);
        h8v a1 = *(const h8v*)(abuf + 1 * 1024 + ln16);
        #pragma unroll
        for (int akb = 0; akb < 16; ++akb) {
            h8v n0 = *(const h8v*)(abuf + ((akb + 1) * 2 + 0) * 1024 + ln16);
            h8v n1 = *(const h8v*)(abuf + ((akb + 1) * 2 + 1) * 1024 + ln16);
            acc0 = __builtin_amdgcn_mfma_f32_32x32x16_f16(a0, bx[akb], acc0, 0, 0, 0);
            acc1 = __builtin_amdgcn_mfma_f32_32x32x16_f16(a1, bx[akb], acc1, 0, 0, 0);
            a0 = n0; a1 = n1;
        }
        acc0 = __builtin_amdgcn_mfma_f32_32x32x16_f16(a0, bn, acc0, 0, 0, 0);
        acc1 = __builtin_amdgcn_mfma_f32_32x32x16_f16(a1, bn, acc1, 0, 0, 0);

        // top-4 update; C/D: col(px)=lane&31, row=(r&3)+8*(r>>2)+4*(lane>>5)
        const int jb = c * 64 + h4;
        #pragma unroll
        for (int r = 0; r < 16; ++r) {
            const int row = (r & 3) + 8 * (r >> 2);
            ins4(pack_si(acc0[r], jb + row),      v);
            ins4(pack_si(acc1[r], jb + 32 + row), v);
        }
    }

    // merge the two k-row halves (lane^32 holds the other 16 rows per block)
    #pragma unroll
    for (int s = 0; s < 4; ++s) ins4(__shfl_xor(v[s], 32, 64), v);

    // ---- fused exact fp32 rescore + z_q write + loss ----
    // wave handles its 32 px; all 64 lanes cooperate per px (lane = 4 channels)
    float wloss = 0.f;
    for (int p = 0; p < 32; ++p) {
        const int pxp = blockIdx.x * 128 + wv * 32 + p;
        const int hwp = pxp & 4095;
        const float* zp = z + (size_t)b * (EMBED_DIM * HW) + hwp;

        float zl[4];
        #pragma unroll
        for (int r = 0; r < 4; ++r)
            zl[r] = zp[(size_t)(lane + 64 * r) * HW];

        int   jj[4];
        float ev[4][4];
        float d[4];
        #pragma unroll
        for (int s = 0; s < 4; ++s) {
            const int js = __float_as_int(__shfl(v[s], p, 64)) & 1023;
            jj[s] = js;
            const float* er = emb + (size_t)js * EMBED_DIM;
            float acc = 0.f;
            #pragma unroll
            for (int r = 0; r < 4; ++r) {
                float e = er[lane + 64 * r];
                ev[s][r] = e;
                float df = e - zl[r];
                acc += df * df;
            }
            d[s] = acc;
        }
        #pragma unroll
        for (int s = 0; s < 4; ++s) {
            #pragma unroll
            for (int off = 32; off; off >>= 1) d[s] += __shfl_down(d[s], off, 64);
            d[s] = __shfl(d[s], 0, 64);           // broadcast exact dist
        }

        // pick best (lowest dist, lowest index on tie) — uniform across lanes
        float bd = d[0]; int bj = jj[0]; int bs = 0;
        #pragma unroll
        for (int s = 1; s < 4; ++s) {
            bool better = (d[s] < bd) || (d[s] == bd && jj[s] < bj);
            bd = better ? d[s] : bd;
            bj = better ? jj[s] : bj;
            bs = better ? s : bs;
        }

        float* op = out + (size_t)b * (EMBED_DIM * HW) + hwp;
        #pragma unroll
        for (int r = 0; r < 4; ++r) {
            float val = (bs == 0) ? ev[0][r]
                      : (bs == 1) ? ev[1][r]
                      : (bs == 2) ? ev[2][r] : ev[3][r];
            op[(size_t)(lane + 64 * r) * HW] = val;
        }
        wloss += bd;                              // uniform; only lane 0's used
    }
    if (lane == 0) atomicAdd(loss_acc, wloss);
}

__global__ void k_final(const float* __restrict__ loss_acc, float* __restrict__ out_loss) {
    *out_loss = (BETA / (float)NPIX / (float)EMBED_DIM) * (*loss_acc);
}

// ======================= fallback (round-1 fp32 path) =======================

__global__ void k_transpose(const float* __restrict__ emb, float* __restrict__ et) {
    int idx = blockIdx.x * blockDim.x + threadIdx.x;
    int c = idx >> 10;
    int j = idx & 1023;
    et[idx] = -2.0f * emb[j * EMBED_DIM + c];
}

__global__ __launch_bounds__(256, 2)
void k_vq(const float* __restrict__ z, const float* __restrict__ emb,
          const float* __restrict__ et, const float* __restrict__ norms,
          float* __restrict__ out, float* __restrict__ loss_acc)
{
    __shared__ float zt[EMBED_DIM * 64];
    __shared__ float redv[16 * 64];
    __shared__ int   redi[16 * 64];
    __shared__ int   widx[64];
    __shared__ float wsum[4];
    const int tid = threadIdx.x;
    const int wg  = blockIdx.x;
    const int p0  = wg * 64;
    const int b   = p0 >> 12;
    const int hw0 = p0 & 4095;
    const float* zbase = z + (size_t)b * (EMBED_DIM * HW) + hw0;
    {
        const int lane16 = tid & 15;
        const int crow   = tid >> 4;
        #pragma unroll
        for (int r = 0; r < 16; ++r) {
            int c = r * 16 + crow;
            float4 vv = *(const float4*)(zbase + (size_t)c * HW + lane16 * 4);
            *(float4*)&zt[c * 64 + lane16 * 4] = vv;
        }
    }
    __syncthreads();
    const int pxg = tid & 15;
    const int cg  = tid >> 4;
    float bestv[4] = {3.4e38f, 3.4e38f, 3.4e38f, 3.4e38f};
    int   besti[4] = {0, 0, 0, 0};
    for (int chunk = 0; chunk < 16; ++chunk) {
        const int jbase = chunk * 64 + cg * 4;
        float acc[4][4];
        #pragma unroll
        for (int i = 0; i < 4; ++i)
            #pragma unroll
            for (int k = 0; k < 4; ++k) acc[i][k] = 0.f;
        const float* ec = et + jbase;
        #pragma unroll 4
        for (int c = 0; c < EMBED_DIM; ++c) {
            float4 za = *(const float4*)&zt[c * 64 + pxg * 4];
            float4 eb = *(const float4*)(ec + (size_t)c * N_EMBED);
            float zi[4] = {za.x, za.y, za.z, za.w};
            float ek[4] = {eb.x, eb.y, eb.z, eb.w};
            #pragma unroll
            for (int i = 0; i < 4; ++i)
                #pragma unroll
                for (int k = 0; k < 4; ++k)
                    acc[i][k] += zi[i] * ek[k];
        }
        float nn[4];
        #pragma unroll
        for (int k = 0; k < 4; ++k) nn[k] = norms[jbase + k];
        #pragma unroll
        for (int i = 0; i < 4; ++i)
            #pragma unroll
            for (int k = 0; k < 4; ++k) {
                float s = nn[k] + acc[i][k];
                if (s < bestv[i]) { bestv[i] = s; besti[i] = jbase + k; }
            }
    }
    #pragma unroll
    for (int i = 0; i < 4; ++i) {
        redv[cg * 64 + pxg * 4 + i] = bestv[i];
        redi[cg * 64 + pxg * 4 + i] = besti[i];
    }
    __syncthreads();
    if (tid < 64) {
        const int px2 = tid;
        float bv = redv[px2];
        int   bi = redi[px2];
        #pragma unroll
        for (int g = 1; g < 16; ++g) {
            float vv = redv[g * 64 + px2];
            int   ix = redi[g * 64 + px2];
            if (vv < bv || (vv == bv && ix < bi)) { bv = vv; bi = ix; }
        }
        widx[px2] = bi;
    }
    __syncthreads();
    const int px = tid & 63;
    const int wv = tid >> 6;
    const int j  = widx[px];
    const float* qrow = emb + (size_t)j * EMBED_DIM;
    float* obase = out + (size_t)b * (EMBED_DIM * HW) + hw0;
    float lsum = 0.f;
    #pragma unroll 4
    for (int cc = 0; cc < 16; ++cc) {
        const int c0 = wv * 64 + cc * 4;
        float4 q = *(const float4*)(qrow + c0);
        float qv[4] = {q.x, q.y, q.z, q.w};
        #pragma unroll
        for (int k = 0; k < 4; ++k) {
            const int c = c0 + k;
            float zv = zt[c * 64 + px];
            float dd = qv[k] - zv;
            lsum += dd * dd;
            obase[(size_t)c * HW + px] = qv[k];
        }
    }
    #pragma unroll
    for (int off = 32; off; off >>= 1) lsum += __shfl_down(lsum, off, 64);
    if ((tid & 63) == 0) wsum[wv] = lsum;
    __syncthreads();
    if (tid == 0) atomicAdd(loss_acc, wsum[0] + wsum[1] + wsum[2] + wsum[3]);
}

// ======================= launch =======================

extern "C" void kernel_launch(void* const* d_in, const int* in_sizes, int n_in,
                              void* d_out, int out_size, void* d_ws, size_t ws_size,
                              hipStream_t stream) {
    const float* z   = (const float*)d_in[0];
    const float* emb = (const float*)d_in[1];
    float* out       = (float*)d_out;
    float* ws        = (float*)d_ws;

    if (ws_size >= NEED_BYTES) {
        float*     loss_acc = ws + NW_LOSS;
        float*     norms    = ws + NW_NORMS;
        _Float16*  es2      = (_Float16*)(ws + NW_ES2);

        k_norms<<<N_EMBED, 64, 0, stream>>>(emb, norms, loss_acc);
        k_prep_e2<<<136, 256, 0, stream>>>(emb, norms, es2);
        k_screen5<<<512, 256, 0, stream>>>(z, es2, emb, out, loss_acc);
        k_final<<<1, 1, 0, stream>>>(loss_acc, out + (size_t)NPIX * EMBED_DIM);
    } else {
        float* loss_acc = ws;
        float* et       = ws + WS_ET_OFF;
        float* norms    = ws + WS_NORM_OFF;
        k_transpose<<<(EMBED_DIM * N_EMBED) / 256, 256, 0, stream>>>(emb, et);
        k_norms<<<N_EMBED, 64, 0, stream>>>(emb, norms, loss_acc);
        k_vq<<<NPIX / 64, 256, 0, stream>>>(z, emb, et, norms, out, loss_acc);
        k_final<<<1, 1, 0, stream>>>(loss_acc, out + (size_t)NPIX * EMBED_DIM);
    }
}